// Round 3
// baseline (560.764 us; speedup 1.0000x reference)
//
#include <hip/hip_runtime.h>
#include <hip/hip_bf16.h>

#define NB   16          // batch
#define NHW  16384       // H*W
#define CHW  1048576     // C*H*W
#define KC   576         // K*C (GEMM K)
#define KN   64          // output channels

typedef __attribute__((ext_vector_type(8))) short bf16x8;
typedef __attribute__((ext_vector_type(4))) float f32x4;
typedef __attribute__((ext_vector_type(2))) int i32x2;

static __device__ __forceinline__ unsigned short f32_to_bf16(float f) {
  unsigned int u = __float_as_uint(f);
  unsigned int r = (u + 0x7FFFu + ((u >> 16) & 1u)) >> 16;  // RNE
  return (unsigned short)r;
}

// ---------------------------------------------------------------------------
// Kernel 1: x [B][CHW] fp32 -> xT [CHW][16] bf16 (32B row = all batches)
// ---------------------------------------------------------------------------
__global__ __launch_bounds__(256) void transpose_x_bf16(
    const float* __restrict__ x, unsigned short* __restrict__ xT) {
  const int i = blockIdx.x * 256 + threadIdx.x;
  unsigned short u[16];
#pragma unroll
  for (int b = 0; b < NB; ++b) u[b] = f32_to_bf16(x[(size_t)b * CHW + i]);
  int4* dst = (int4*)(xT + (size_t)i * NB);
  dst[0] = ((int4*)u)[0];
  dst[1] = ((int4*)u)[1];
}

// ---------------------------------------------------------------------------
// Kernel 2: pack w [KN][KC] fp32 into MFMA A-fragment order, bf16:
// wP[((ks*4+m)*64 + lane)*8 + j] = w[m*16 + (lane&15)][ks*32 + (lane>>4)*8 + j]
// ---------------------------------------------------------------------------
__global__ __launch_bounds__(256) void prep_w(
    const float* __restrict__ w, unsigned short* __restrict__ wP) {
  const int t = blockIdx.x * 256 + threadIdx.x;
  const int j  = t & 7;
  const int l  = (t >> 3) & 63;
  const int m  = (t >> 9) & 3;
  const int ks = t >> 11;                        // 0..17
  const int n  = m * 16 + (l & 15);
  const int k  = ks * 32 + (l >> 4) * 8 + j;
  wP[t] = f32_to_bf16(w[(size_t)n * KC + k]);
}

static __device__ __forceinline__ bf16x8 make_bfr(i32x2 t0, i32x2 t1) {
  union { int i[4]; bf16x8 v; } u;
  u.i[0] = t0.x; u.i[1] = t0.y; u.i[2] = t1.x; u.i[3] = t1.y;
  return u.v;
}

// ---------------------------------------------------------------------------
// Main kernel. Block = 256 thr = 4 waves, 16 pixels; wave wv owns pixels
// p0+4wv .. p0+4wv+3 and a PRIVATE 8KB LDS region -> no main-loop barriers.
// Per wave: GEMM out[64n x 64cols], cols = px*16 + b. K in 9 chunks of 64.
// Staging: lane gathers full 32B xT rows (px=lane>>4, q=(lane&15)+16i),
// writes 2x ds_write_b128 into subtiled layout (slot order 0,2,4,6,1,3,5,7;
// 128B-aligned subtiles [4 k][16 b]); B-fragments read via ds_read_b64_tr_b16.
// ---------------------------------------------------------------------------
__global__ __launch_bounds__(256, 3) void hashconv_mfma(
    const int* __restrict__ ht, const unsigned short* __restrict__ xT,
    const unsigned short* __restrict__ wP, float* __restrict__ out) {
  const int tid  = threadIdx.x;
  const int lane = tid & 63;
  const int wv   = tid >> 6;
  const int hi   = lane >> 4;   // staging: px ; mfma: k-group
  const int b16i = lane & 15;   // staging: q low / mfma: batch col
  const int p0   = blockIdx.x * 16;

  __shared__ char Ls[32768];

  // ---- staging write base: rows q=(b16i)+16i of px=hi ----
  const int kb0 = b16i >> 2;
  const int m0  = (kb0 & 1) * 4 + (kb0 >> 1);          // slot of kb0
  char* wbase = Ls + wv * 8192 + hi * 2048 + m0 * 128 + (b16i & 3) * 32;
  const int sel = lane & 1;
  const int o0  = sel << 4;                            // bank-parity interleave

  // ---- tr-read per-lane address (32-bit LDS offset) ----
  const unsigned ldsbase = (unsigned)(size_t)&Ls[0];
  const unsigned tb = ldsbase + wv * 8192 + b16i * 8 + hi * 128;

  const int* htb = ht + (size_t)(p0 + 4 * wv + hi) * KC + b16i;
  const unsigned short* wPl = wP + lane * 8;

  f32x4 acc[4][4];  // [m][px]
#pragma unroll
  for (int m = 0; m < 4; ++m)
#pragma unroll
    for (int px = 0; px < 4; ++px) acc[m][px] = (f32x4){0.f, 0.f, 0.f, 0.f};

  int4 g[4][2];
  int  idxs[2][4];

  // ---- prologue: idx(0), idx(1), issue gathers(0) ----
#pragma unroll
  for (int i = 0; i < 4; ++i) idxs[0][i] = htb[16 * i];
#pragma unroll
  for (int i = 0; i < 4; ++i) idxs[1][i] = htb[64 + 16 * i];
#pragma unroll
  for (int i = 0; i < 4; ++i) {
    const unsigned short* s = xT + (size_t)(unsigned)idxs[0][i] * NB;
    g[i][0] = *(const int4*)(s);
    g[i][1] = *(const int4*)(s + 8);
  }

#pragma unroll
  for (int kc = 0; kc < 9; ++kc) {
    // 1. write chunk kc rows to LDS (parity-interleaved halves)
#pragma unroll
    for (int i = 0; i < 4; ++i) {
      const int off = (i & 1) * 256 + (i >> 1) * 1024;
      int4 lo = g[i][0], hh = g[i][1];
      *(int4*)(wbase + off + o0)        = sel ? hh : lo;
      *(int4*)(wbase + off + (o0 ^ 16)) = sel ? lo : hh;
    }
    // 2. issue gathers for chunk kc+1 (fly during compute below)
    if (kc < 8) {
#pragma unroll
      for (int i = 0; i < 4; ++i) {
        const unsigned short* s =
            xT + (size_t)(unsigned)idxs[(kc + 1) & 1][i] * NB;
        g[i][0] = *(const int4*)(s);
        g[i][1] = *(const int4*)(s + 8);
      }
    }
    // 3. prefetch indices for chunk kc+2
    if (kc < 7) {
#pragma unroll
      for (int i = 0; i < 4; ++i) idxs[kc & 1][i] = htb[(kc + 2) * 64 + 16 * i];
    }
    // 4. drain LDS writes (same-wave RAW)
    asm volatile("s_waitcnt lgkmcnt(0)" ::: "memory");
    // 5. compute: 2 k-steps of 32
#pragma unroll
    for (int ks = 0; ks < 2; ++ks) {
      bf16x8 afr[4];
#pragma unroll
      for (int m = 0; m < 4; ++m)
        afr[m] = *(const bf16x8*)(wPl + (size_t)((kc * 2 + ks) * 4 + m) * 512);
      i32x2 t[4][2];
#pragma unroll
      for (int px = 0; px < 4; ++px)
#pragma unroll
        for (int jh = 0; jh < 2; ++jh)
          asm volatile("ds_read_b64_tr_b16 %0, %1 offset:%2"
                       : "=v"(t[px][jh])
                       : "v"(tb), "i"(px * 2048 + ks * 1024 + jh * 512)
                       : "memory");
      asm volatile("s_waitcnt lgkmcnt(0)" ::: "memory");
      __builtin_amdgcn_sched_barrier(0);
      bf16x8 bfr[4];
#pragma unroll
      for (int px = 0; px < 4; ++px) bfr[px] = make_bfr(t[px][0], t[px][1]);
#pragma unroll
      for (int m = 0; m < 4; ++m)
#pragma unroll
        for (int px = 0; px < 4; ++px)
          acc[m][px] = __builtin_amdgcn_mfma_f32_16x16x32_bf16(
              afr[m], bfr[px], acc[m][px], 0, 0, 0);
    }
  }

  // ---- epilogue: LDS transpose -> coalesced 64B stores ----
  // C/D: col = b16i = batch, row(n in m-tile) = hi*4+j, pixel = 4wv+px
  float* Ep = (float*)Ls;  // 256*20*4 = 20.5KB < 32KB
  const int tb_ = tid >> 4, tn = tid & 15;
#pragma unroll 1
  for (int m = 0; m < 4; ++m) {
    __syncthreads();
#pragma unroll
    for (int px = 0; px < 4; ++px)
#pragma unroll
      for (int j = 0; j < 4; ++j)
        Ep[(b16i * 16 + hi * 4 + j) * 20 + 4 * wv + px] = acc[m][px][j];
    __syncthreads();
    const float* src = &Ep[(tb_ * 16 + tn) * 20];
    float4 v0 = *(const float4*)(src + 0);
    float4 v1 = *(const float4*)(src + 4);
    float4 v2 = *(const float4*)(src + 8);
    float4 v3 = *(const float4*)(src + 12);
    float4* dst = (float4*)(out + ((size_t)(tb_ * 64 + m * 16 + tn)) * NHW + p0);
    dst[0] = v0; dst[1] = v1; dst[2] = v2; dst[3] = v3;
  }
}

// ---------------------------------------------------------------------------
// Fallback (workspace too small): direct gather, slow but correct.
// ---------------------------------------------------------------------------
__global__ __launch_bounds__(256) void hashconv_naive_kernel(
    const int* __restrict__ ht, const float* __restrict__ x,
    const float* __restrict__ w, float* __restrict__ out) {
  const int wave = (blockIdx.x * 256 + threadIdx.x) >> 6;
  const int lane = threadIdx.x & 63;
  const int b = wave >> 14;
  const int p = wave & (NHW - 1);
  float acc = 0.f;
  for (int q = 0; q < KC; ++q) {
    const int idx = __builtin_amdgcn_readlane(ht[(size_t)p * KC + q], 0);
    const float xv = x[(size_t)b * CHW + idx];
    acc = fmaf(w[(size_t)lane * KC + q], xv, acc);
  }
  out[((size_t)(b * 64 + lane)) * NHW + p] = acc;
}

extern "C" void kernel_launch(void* const* d_in, const int* in_sizes, int n_in,
                              void* d_out, int out_size, void* d_ws, size_t ws_size,
                              hipStream_t stream) {
  const float* x  = (const float*)d_in[0];
  const int*   ht = (const int*)d_in[1];
  const float* w  = (const float*)d_in[2];
  float* out = (float*)d_out;

  const size_t xT_elems = (size_t)CHW * NB;      // bf16
  const size_t wP_elems = (size_t)18 * 4 * 64 * 8;
  const size_t need = (xT_elems + wP_elems) * sizeof(unsigned short);

  if (ws_size >= need) {
    unsigned short* xT = (unsigned short*)d_ws;
    unsigned short* wP = xT + xT_elems;
    transpose_x_bf16<<<CHW / 256, 256, 0, stream>>>(x, xT);
    prep_w<<<(int)(wP_elems / 256), 256, 0, stream>>>(w, wP);
    hashconv_mfma<<<NHW / 16, 256, 0, stream>>>(ht, xT, wP, out);
  } else {
    hashconv_naive_kernel<<<(NB * NHW * 64) / 256, 256, 0, stream>>>(ht, x, w, out);
  }
}

// Round 4
// 478.535 us; speedup vs baseline: 1.1718x; 1.1718x over previous
//
#include <hip/hip_runtime.h>
#include <hip/hip_bf16.h>

#define NB   16          // batch
#define NHW  16384       // H*W
#define CHW  1048576     // C*H*W
#define KC   576         // K*C (GEMM K)
#define KN   64          // output channels

typedef __attribute__((ext_vector_type(8))) short bf16x8;
typedef __attribute__((ext_vector_type(4))) float f32x4;
typedef __attribute__((ext_vector_type(2))) int i32x2;

static __device__ __forceinline__ unsigned short f32_to_bf16(float f) {
  unsigned int u = __float_as_uint(f);
  unsigned int r = (u + 0x7FFFu + ((u >> 16) & 1u)) >> 16;  // RNE
  return (unsigned short)r;
}

// ---------------------------------------------------------------------------
// Kernel 1: x [B][CHW] fp32 -> xT [CHW][16] bf16 (32B row = all batches)
// ---------------------------------------------------------------------------
__global__ __launch_bounds__(256) void transpose_x_bf16(
    const float* __restrict__ x, unsigned short* __restrict__ xT) {
  const int i = blockIdx.x * 256 + threadIdx.x;
  unsigned short u[16];
#pragma unroll
  for (int b = 0; b < NB; ++b) u[b] = f32_to_bf16(x[(size_t)b * CHW + i]);
  int4* dst = (int4*)(xT + (size_t)i * NB);
  dst[0] = ((int4*)u)[0];
  dst[1] = ((int4*)u)[1];
}

// ---------------------------------------------------------------------------
// Kernel 2: pack w [KN][KC] fp32 into MFMA A-fragment order, bf16:
// wP[((ks*4+m)*64 + lane)*8 + j] = w[m*16 + (lane&15)][ks*32 + (lane>>4)*8 + j]
// ---------------------------------------------------------------------------
__global__ __launch_bounds__(256) void prep_w(
    const float* __restrict__ w, unsigned short* __restrict__ wP) {
  const int t = blockIdx.x * 256 + threadIdx.x;
  const int j  = t & 7;
  const int l  = (t >> 3) & 63;
  const int m  = (t >> 9) & 3;
  const int ks = t >> 11;                        // 0..17
  const int n  = m * 16 + (l & 15);
  const int k  = ks * 32 + (l >> 4) * 8 + j;
  wP[t] = f32_to_bf16(w[(size_t)n * KC + k]);
}

static __device__ __forceinline__ bf16x8 make_bfr(i32x2 t0, i32x2 t1) {
  union { int i[4]; bf16x8 v; } u;
  u.i[0] = t0.x; u.i[1] = t0.y; u.i[2] = t1.x; u.i[3] = t1.y;
  return u.v;
}

// ---------------------------------------------------------------------------
// Main kernel. Block = 256 thr = 4 waves, 16 pixels; wave wv owns pixels
// p0+4wv..p0+4wv+3 and a PRIVATE 8KB LDS region -> no main-loop barriers.
// K processed in 18 steps of 32 (one 16x16x32 k-step each). Per step a lane
// gathers TWO 32B xT rows (q = 32*st + b16i, +16), writes them as 4x
// ds_write_b128 into the tr-readable subtile layout (R3-proven addressing),
// reads B-fragments via ds_read_b64_tr_b16, and does 16 MFMAs.
// Shallow pipeline: idx prefetched 2 steps ahead, gathers 1 step ahead.
// Register budget kept ~150 to avoid the R3 scratch-spill disaster.
// ---------------------------------------------------------------------------
__global__ __launch_bounds__(256, 3) void hashconv_mfma(
    const int* __restrict__ ht, const unsigned short* __restrict__ xT,
    const unsigned short* __restrict__ wP, float* __restrict__ out) {
  const int tid  = threadIdx.x;
  const int lane = tid & 63;
  const int wv   = tid >> 6;
  const int hi   = lane >> 4;   // staging: px ; mfma: k-group
  const int b16i = lane & 15;   // staging: q low ; mfma: batch col
  const int p0   = blockIdx.x * 16;

  __shared__ char Ls[32768];

  // ---- staging write base (R3-proven layout) ----
  const int kb0 = b16i >> 2;
  const int m0  = (kb0 & 1) * 4 + (kb0 >> 1);
  char* wbase = Ls + wv * 8192 + hi * 2048 + m0 * 128 + (b16i & 3) * 32;
  const int sel = lane & 1;
  const int o0  = sel << 4;     // bank-parity interleave of the two 16B halves

  // ---- tr-read per-lane base (R3-proven) ----
  const unsigned ldsbase = (unsigned)(size_t)&Ls[0];
  const unsigned trb = ldsbase + wv * 8192 + b16i * 8 + hi * 128;

  const int* htb = ht + (size_t)(p0 + 4 * wv + hi) * KC + b16i;
  const unsigned short* wPl = wP + lane * 8;

  f32x4 acc[4][4];  // [m][px]
#pragma unroll
  for (int m = 0; m < 4; ++m)
#pragma unroll
    for (int px = 0; px < 4; ++px) acc[m][px] = (f32x4){0.f, 0.f, 0.f, 0.f};

  // current step rows (32B each) and next-step prefetch
  int4 r0lo, r0hi, r1lo, r1hi;
  int4 n0lo, n0hi, n1lo, n1hi;
  int ib0, ib1;   // idx for step st+1
  int na0, na1;   // idx for step st+2

  // ---- prologue ----
  {
    const int j0 = htb[0], j1 = htb[16];   // idx step 0
    ib0 = htb[32]; ib1 = htb[48];          // idx step 1
    const unsigned short* s0 = xT + (size_t)(unsigned)j0 * NB;
    const unsigned short* s1 = xT + (size_t)(unsigned)j1 * NB;
    r0lo = *(const int4*)(s0); r0hi = *(const int4*)(s0 + 8);
    r1lo = *(const int4*)(s1); r1hi = *(const int4*)(s1 + 8);
  }

#pragma unroll
  for (int st = 0; st < 18; ++st) {
    const int koff = (st & 1) * 1024;
    // 1. write current step's two rows (iglob even at +0, odd at +256)
    *(int4*)(wbase + koff + o0)              = sel ? r0hi : r0lo;
    *(int4*)(wbase + koff + (o0 ^ 16))       = sel ? r0lo : r0hi;
    *(int4*)(wbase + koff + 256 + o0)        = sel ? r1hi : r1lo;
    *(int4*)(wbase + koff + 256 + (o0 ^ 16)) = sel ? r1lo : r1hi;
    // 2. idx prefetch for step st+2
    if (st < 16) {
      na0 = htb[(st + 2) * 32];
      na1 = htb[(st + 2) * 32 + 16];
    }
    // 3. gather prefetch for step st+1 (flies under this step's MFMA)
    if (st < 17) {
      const unsigned short* s0 = xT + (size_t)(unsigned)ib0 * NB;
      const unsigned short* s1 = xT + (size_t)(unsigned)ib1 * NB;
      n0lo = *(const int4*)(s0); n0hi = *(const int4*)(s0 + 8);
      n1lo = *(const int4*)(s1); n1hi = *(const int4*)(s1 + 8);
    }
    // 4. drain LDS writes (same-wave RAW; DS-only counter, globals unaffected)
    asm volatile("s_waitcnt lgkmcnt(0)" ::: "memory");
    // 5. tr-reads of this step's B fragments
    i32x2 t[4][2];
#pragma unroll
    for (int px = 0; px < 4; ++px)
#pragma unroll
      for (int jh = 0; jh < 2; ++jh)
        asm volatile("ds_read_b64_tr_b16 %0, %1 offset:%2"
                     : "=v"(t[px][jh])
                     : "v"(trb), "i"(px * 2048 + (st & 1) * 1024 + jh * 512)
                     : "memory");
    asm volatile("s_waitcnt lgkmcnt(0)" ::: "memory");
    __builtin_amdgcn_sched_barrier(0);
    bf16x8 bfr[4];
#pragma unroll
    for (int px = 0; px < 4; ++px) bfr[px] = make_bfr(t[px][0], t[px][1]);
    // 6. MFMA: afr loaded per-m (low pressure; scheduler hoists if regs allow)
#pragma unroll
    for (int m = 0; m < 4; ++m) {
      const bf16x8 afr = *(const bf16x8*)(wPl + (size_t)(st * 4 + m) * 512);
#pragma unroll
      for (int px = 0; px < 4; ++px)
        acc[m][px] = __builtin_amdgcn_mfma_f32_16x16x32_bf16(
            afr, bfr[px], acc[m][px], 0, 0, 0);
    }
    // 7. rotate pipeline registers
    r0lo = n0lo; r0hi = n0hi; r1lo = n1lo; r1hi = n1hi;
    ib0 = na0; ib1 = na1;
  }

  // ---- epilogue: LDS transpose -> fully-coalesced 64B-line stores ----
  // C/D: col(lane&15)=batch, row in m-tile = hi*4+j, pixel = 4wv+px
  float* Ep = (float*)Ls;  // 256 rows x 20 floats = 20.5 KB
  const int er = tid >> 2;   // 0..63
  const int ec = tid & 3;    // 16B chunk within the 64B line
#pragma unroll 1
  for (int m = 0; m < 4; ++m) {
    __syncthreads();
#pragma unroll
    for (int px = 0; px < 4; ++px)
#pragma unroll
      for (int j = 0; j < 4; ++j)
        Ep[(b16i * 16 + hi * 4 + j) * 20 + 4 * wv + px] = acc[m][px][j];
    __syncthreads();
#pragma unroll
    for (int it = 0; it < 4; ++it) {
      const int r2 = it * 64 + er;           // r2 = b*16 + nsub
      const float4 v = *(const float4*)(&Ep[r2 * 20 + ec * 4]);
      *(float4*)(out + ((size_t)((r2 >> 4) * 64 + m * 16 + (r2 & 15))) * NHW +
                 p0 + ec * 4) = v;           // lanes 0-3 fill one 64B line
    }
  }
}

// ---------------------------------------------------------------------------
// Fallback (workspace too small): direct gather, slow but correct.
// ---------------------------------------------------------------------------
__global__ __launch_bounds__(256) void hashconv_naive_kernel(
    const int* __restrict__ ht, const float* __restrict__ x,
    const float* __restrict__ w, float* __restrict__ out) {
  const int wave = (blockIdx.x * 256 + threadIdx.x) >> 6;
  const int lane = threadIdx.x & 63;
  const int b = wave >> 14;
  const int p = wave & (NHW - 1);
  float acc = 0.f;
  for (int q = 0; q < KC; ++q) {
    const int idx = __builtin_amdgcn_readlane(ht[(size_t)p * KC + q], 0);
    const float xv = x[(size_t)b * CHW + idx];
    acc = fmaf(w[(size_t)lane * KC + q], xv, acc);
  }
  out[((size_t)(b * 64 + lane)) * NHW + p] = acc;
}

extern "C" void kernel_launch(void* const* d_in, const int* in_sizes, int n_in,
                              void* d_out, int out_size, void* d_ws, size_t ws_size,
                              hipStream_t stream) {
  const float* x  = (const float*)d_in[0];
  const int*   ht = (const int*)d_in[1];
  const float* w  = (const float*)d_in[2];
  float* out = (float*)d_out;

  const size_t xT_elems = (size_t)CHW * NB;      // bf16
  const size_t wP_elems = (size_t)18 * 4 * 64 * 8;
  const size_t need = (xT_elems + wP_elems) * sizeof(unsigned short);

  if (ws_size >= need) {
    unsigned short* xT = (unsigned short*)d_ws;
    unsigned short* wP = xT + xT_elems;
    transpose_x_bf16<<<CHW / 256, 256, 0, stream>>>(x, xT);
    prep_w<<<(int)(wP_elems / 256), 256, 0, stream>>>(w, wP);
    hashconv_mfma<<<NHW / 16, 256, 0, stream>>>(ht, xT, wP, out);
  } else {
    hashconv_naive_kernel<<<(NB * NHW * 64) / 256, 256, 0, stream>>>(ht, x, w, out);
  }
}

// Round 5
// 356.696 us; speedup vs baseline: 1.5721x; 1.3416x over previous
//
#include <hip/hip_runtime.h>
#include <hip/hip_bf16.h>

#define NB   16          // batch
#define NHW  16384       // H*W
#define CHW  1048576     // C*H*W
#define KC   576         // K*C (GEMM K)
#define KN   64          // output channels

typedef __attribute__((ext_vector_type(8))) short bf16x8;
typedef __attribute__((ext_vector_type(4))) float f32x4;
typedef __attribute__((ext_vector_type(2))) int i32x2;
typedef __attribute__((ext_vector_type(4))) int i32x4;

static __device__ __forceinline__ unsigned short f32_to_bf16(float f) {
  unsigned int u = __float_as_uint(f);
  unsigned int r = (u + 0x7FFFu + ((u >> 16) & 1u)) >> 16;  // RNE
  return (unsigned short)r;
}

static __device__ __forceinline__ void gload16(const void* g, void* l) {
  __builtin_amdgcn_global_load_lds(
      (const __attribute__((address_space(1))) void*)g,
      (__attribute__((address_space(3))) void*)l, 16, 0, 0);
}

static __device__ __forceinline__ bf16x8 pack_bfr(i32x2 a, i32x2 b) {
  i32x4 v; v.x = a.x; v.y = a.y; v.z = b.x; v.w = b.y;
  return __builtin_bit_cast(bf16x8, v);
}

// ---------------------------------------------------------------------------
// Kernel 1: x [B][CHW] fp32 -> xT [CHW][16] bf16 (32B row = all batches)
// ---------------------------------------------------------------------------
__global__ __launch_bounds__(256) void transpose_x_bf16(
    const float* __restrict__ x, unsigned short* __restrict__ xT) {
  const int i = blockIdx.x * 256 + threadIdx.x;
  unsigned short u[16];
#pragma unroll
  for (int b = 0; b < NB; ++b) u[b] = f32_to_bf16(x[(size_t)b * CHW + i]);
  int4* dst = (int4*)(xT + (size_t)i * NB);
  dst[0] = ((int4*)u)[0];
  dst[1] = ((int4*)u)[1];
}

// ---------------------------------------------------------------------------
// Kernel 2: pack w [KN][KC] fp32 into MFMA A-fragment order, bf16:
// wP[((ks*4+m)*64 + lane)*8 + j] = w[m*16 + (lane&15)][ks*32 + (lane>>4)*8 + j]
// ---------------------------------------------------------------------------
__global__ __launch_bounds__(256) void prep_w(
    const float* __restrict__ w, unsigned short* __restrict__ wP) {
  const int t = blockIdx.x * 256 + threadIdx.x;
  const int j  = t & 7;
  const int l  = (t >> 3) & 63;
  const int m  = (t >> 9) & 3;
  const int ks = t >> 11;                        // 0..17
  const int n  = m * 16 + (l & 15);
  const int k  = ks * 32 + (l >> 4) * 8 + j;
  wP[t] = f32_to_bf16(w[(size_t)n * KC + k]);
}

// ---------------------------------------------------------------------------
// Main kernel. 4 waves/block, 16 pixels; wave wv owns 4 pixels and a private
// LDS slice -> NO barriers in the main loop. 18 k-steps of 32.
// Gather staging is pure global_load_lds DMA: linear LDS dest chunks,
// per-lane pre-permuted global source (lane i of instr j fetches half
// (i&1) of xT row ht[px=j][k(i)]), reproducing the R3/R4-verified
// tr_b16-readable subtile layout:
//   A(k,px,c) = px*1024 + (s&1)*512 + (s>>1)*128 + (k&3)*32 + c*2, s=k>>2
// Double-buffered: buf b at b*16KB + wv*4KB. Counted vmcnt, idx 2 ahead.
// ---------------------------------------------------------------------------
__global__ __launch_bounds__(256, 3) void hashconv_mfma(
    const int* __restrict__ ht, const unsigned short* __restrict__ xT,
    const unsigned short* __restrict__ wP, float* __restrict__ out) {
  const int tid  = threadIdx.x;
  const int lane = tid & 63;
  const int wv   = __builtin_amdgcn_readfirstlane(tid >> 6);
  const int hi   = lane >> 4;
  const int b16i = lane & 15;
  const int p0   = blockIdx.x * 16;

  __shared__ char Ls[32768];

  // per-lane DMA source decode (see header comment)
  const int kk   = ((lane >> 3) & 3) * 8 + (lane >> 5) * 4 + ((lane >> 1) & 3);
  const int chof = (lane & 1) * 16;   // which 16B half of the 32B xT row

  // tr-read per-lane bases (R3/R4-proven addressing), one per buffer
  const unsigned ldsbase = (unsigned)(size_t)&Ls[0];
  const unsigned trb0 = ldsbase + wv * 4096 + hi * 128 + b16i * 8;
  const unsigned trb1 = trb0 + 16384;

  const int* htj = ht + (size_t)(p0 + 4 * wv) * KC + kk;
  const unsigned short* wPl = wP + lane * 8;
  const char* xTb = (const char*)xT;

  f32x4 acc[4][4];  // [m][px], all indices compile-time under full unroll
#pragma unroll
  for (int m = 0; m < 4; ++m)
#pragma unroll
    for (int px = 0; px < 4; ++px) acc[m][px] = (f32x4){0.f, 0.f, 0.f, 0.f};

  // ---- prologue: idx(0), idx(1), DMA(0) into buf0 ----
  int i00 = htj[0 * KC], i01 = htj[1 * KC], i02 = htj[2 * KC], i03 = htj[3 * KC];
  int c0 = htj[0 * KC + 32], c1 = htj[1 * KC + 32];
  int c2 = htj[2 * KC + 32], c3 = htj[3 * KC + 32];
  {
    char* db = Ls + (wv << 12);
    gload16(xTb + (size_t)(unsigned)i00 * 32 + chof, db);
    gload16(xTb + (size_t)(unsigned)i01 * 32 + chof, db + 1024);
    gload16(xTb + (size_t)(unsigned)i02 * 32 + chof, db + 2048);
    gload16(xTb + (size_t)(unsigned)i03 * 32 + chof, db + 3072);
  }

#pragma unroll
  for (int st = 0; st < 18; ++st) {
    int n0 = 0, n1 = 0, n2 = 0, n3 = 0;
    // ph1: idx prefetch for st+2
    if (st < 16) {
      n0 = htj[0 * KC + (st + 2) * 32];
      n1 = htj[1 * KC + (st + 2) * 32];
      n2 = htj[2 * KC + (st + 2) * 32];
      n3 = htj[3 * KC + (st + 2) * 32];
    }
    // ph2: DMA gather for st+1 into the other buffer
    if (st < 17) {
      char* db = Ls + (((st + 1) & 1) << 14) + (wv << 12);
      gload16(xTb + (size_t)(unsigned)c0 * 32 + chof, db);
      gload16(xTb + (size_t)(unsigned)c1 * 32 + chof, db + 1024);
      gload16(xTb + (size_t)(unsigned)c2 * 32 + chof, db + 2048);
      gload16(xTb + (size_t)(unsigned)c3 * 32 + chof, db + 3072);
    }
    // ph3: counted drain — exactly this step's DMA done, prefetch in flight
    if (st <= 15)      asm volatile("s_waitcnt vmcnt(8)" ::: "memory");
    else if (st == 16) asm volatile("s_waitcnt vmcnt(4)" ::: "memory");
    else               asm volatile("s_waitcnt vmcnt(0)" ::: "memory");
    // ph4: tr-reads (named scalars only) + MFMA
    const unsigned trb = (st & 1) ? trb1 : trb0;
    i32x2 t00, t01, t10, t11, t20, t21, t30, t31;
    asm volatile("ds_read_b64_tr_b16 %0, %1 offset:0"    : "=v"(t00) : "v"(trb) : "memory");
    asm volatile("ds_read_b64_tr_b16 %0, %1 offset:512"  : "=v"(t01) : "v"(trb) : "memory");
    asm volatile("ds_read_b64_tr_b16 %0, %1 offset:1024" : "=v"(t10) : "v"(trb) : "memory");
    asm volatile("ds_read_b64_tr_b16 %0, %1 offset:1536" : "=v"(t11) : "v"(trb) : "memory");
    asm volatile("ds_read_b64_tr_b16 %0, %1 offset:2048" : "=v"(t20) : "v"(trb) : "memory");
    asm volatile("ds_read_b64_tr_b16 %0, %1 offset:2560" : "=v"(t21) : "v"(trb) : "memory");
    asm volatile("ds_read_b64_tr_b16 %0, %1 offset:3072" : "=v"(t30) : "v"(trb) : "memory");
    asm volatile("ds_read_b64_tr_b16 %0, %1 offset:3584" : "=v"(t31) : "v"(trb) : "memory");
    asm volatile("s_waitcnt lgkmcnt(0)" ::: "memory");
    __builtin_amdgcn_sched_barrier(0);
    const bf16x8 bfr0 = pack_bfr(t00, t01);
    const bf16x8 bfr1 = pack_bfr(t10, t11);
    const bf16x8 bfr2 = pack_bfr(t20, t21);
    const bf16x8 bfr3 = pack_bfr(t30, t31);
#pragma unroll
    for (int m = 0; m < 4; ++m) {
      const bf16x8 afr = *(const bf16x8*)(wPl + (size_t)(st * 4 + m) * 512);
      acc[m][0] = __builtin_amdgcn_mfma_f32_16x16x32_bf16(afr, bfr0, acc[m][0], 0, 0, 0);
      acc[m][1] = __builtin_amdgcn_mfma_f32_16x16x32_bf16(afr, bfr1, acc[m][1], 0, 0, 0);
      acc[m][2] = __builtin_amdgcn_mfma_f32_16x16x32_bf16(afr, bfr2, acc[m][2], 0, 0, 0);
      acc[m][3] = __builtin_amdgcn_mfma_f32_16x16x32_bf16(afr, bfr3, acc[m][3], 0, 0, 0);
    }
    // rotate idx pipeline
    if (st < 16) { c0 = n0; c1 = n1; c2 = n2; c3 = n3; }
  }

  // ---- epilogue: LDS transpose -> fully-coalesced 64B-line stores ----
  // C/D: col(lane&15)=batch, row in m-tile = hi*4+j, pixel = 4wv+px
  float* Ep = (float*)Ls;  // 256 rows x 20 floats = 20.5 KB
  const int er = tid >> 2;   // 0..63
  const int ec = tid & 3;    // 16B chunk within the 64B line
#pragma unroll 1
  for (int m = 0; m < 4; ++m) {
    __syncthreads();
#pragma unroll
    for (int px = 0; px < 4; ++px)
#pragma unroll
      for (int j = 0; j < 4; ++j)
        Ep[(b16i * 16 + hi * 4 + j) * 20 + 4 * wv + px] = acc[m][px][j];
    __syncthreads();
#pragma unroll
    for (int it = 0; it < 4; ++it) {
      const int r2 = it * 64 + er;           // r2 = b*16 + nsub
      const float4 v = *(const float4*)(&Ep[r2 * 20 + ec * 4]);
      *(float4*)(out + ((size_t)((r2 >> 4) * 64 + m * 16 + (r2 & 15))) * NHW +
                 p0 + ec * 4) = v;           // lanes 0-3 fill one 64B line
    }
  }
}

// ---------------------------------------------------------------------------
// Fallback (workspace too small): direct gather, slow but correct.
// ---------------------------------------------------------------------------
__global__ __launch_bounds__(256) void hashconv_naive_kernel(
    const int* __restrict__ ht, const float* __restrict__ x,
    const float* __restrict__ w, float* __restrict__ out) {
  const int wave = (blockIdx.x * 256 + threadIdx.x) >> 6;
  const int lane = threadIdx.x & 63;
  const int b = wave >> 14;
  const int p = wave & (NHW - 1);
  float acc = 0.f;
  for (int q = 0; q < KC; ++q) {
    const int idx = __builtin_amdgcn_readlane(ht[(size_t)p * KC + q], 0);
    const float xv = x[(size_t)b * CHW + idx];
    acc = fmaf(w[(size_t)lane * KC + q], xv, acc);
  }
  out[((size_t)(b * 64 + lane)) * NHW + p] = acc;
}

extern "C" void kernel_launch(void* const* d_in, const int* in_sizes, int n_in,
                              void* d_out, int out_size, void* d_ws, size_t ws_size,
                              hipStream_t stream) {
  const float* x  = (const float*)d_in[0];
  const int*   ht = (const int*)d_in[1];
  const float* w  = (const float*)d_in[2];
  float* out = (float*)d_out;

  const size_t xT_elems = (size_t)CHW * NB;      // bf16
  const size_t wP_elems = (size_t)18 * 4 * 64 * 8;
  const size_t need = (xT_elems + wP_elems) * sizeof(unsigned short);

  if (ws_size >= need) {
    unsigned short* xT = (unsigned short*)d_ws;
    unsigned short* wP = xT + xT_elems;
    transpose_x_bf16<<<CHW / 256, 256, 0, stream>>>(x, xT);
    prep_w<<<(int)(wP_elems / 256), 256, 0, stream>>>(w, wP);
    hashconv_mfma<<<NHW / 16, 256, 0, stream>>>(ht, xT, wP, out);
  } else {
    hashconv_naive_kernel<<<(NB * NHW * 64) / 256, 256, 0, stream>>>(ht, x, w, out);
  }
}

// Round 6
// 225.558 us; speedup vs baseline: 2.4861x; 1.5814x over previous
//
#include <hip/hip_runtime.h>
#include <hip/hip_bf16.h>

#define NB   16          // batch
#define NHW  16384       // H*W
#define CHW  1048576     // C*H*W
#define KC   576         // K*C (GEMM K)
#define KN   64          // output channels

typedef __attribute__((ext_vector_type(8))) short bf16x8;
typedef __attribute__((ext_vector_type(4))) float f32x4;
typedef __attribute__((ext_vector_type(2))) int i32x2;
typedef __attribute__((ext_vector_type(4))) int i32x4;

static __device__ __forceinline__ unsigned short f32_to_bf16(float f) {
  unsigned int u = __float_as_uint(f);
  unsigned int r = (u + 0x7FFFu + ((u >> 16) & 1u)) >> 16;  // RNE
  return (unsigned short)r;
}

static __device__ __forceinline__ void gload16(const void* g, void* l) {
  __builtin_amdgcn_global_load_lds(
      (const __attribute__((address_space(1))) void*)g,
      (__attribute__((address_space(3))) void*)l, 16, 0, 0);
}

static __device__ __forceinline__ bf16x8 pack_bfr(i32x2 a, i32x2 b) {
  i32x4 v; v.x = a.x; v.y = a.y; v.z = b.x; v.w = b.y;
  return __builtin_bit_cast(bf16x8, v);
}

// ---------------------------------------------------------------------------
// Kernel 1: x [B][CHW] fp32 -> xT [CHW][16] bf16 (32B row = all batches)
// ---------------------------------------------------------------------------
__global__ __launch_bounds__(256) void transpose_x_bf16(
    const float* __restrict__ x, unsigned short* __restrict__ xT) {
  const int i = blockIdx.x * 256 + threadIdx.x;
  unsigned short u[16];
#pragma unroll
  for (int b = 0; b < NB; ++b) u[b] = f32_to_bf16(x[(size_t)b * CHW + i]);
  int4* dst = (int4*)(xT + (size_t)i * NB);
  dst[0] = ((int4*)u)[0];
  dst[1] = ((int4*)u)[1];
}

// ---------------------------------------------------------------------------
// Kernel 2: pack w [KN][KC] fp32 into MFMA A-fragment order, bf16:
// wP[((ks*4+m)*64 + lane)*8 + j] = w[m*16 + (lane&15)][ks*32 + (lane>>4)*8 + j]
// ---------------------------------------------------------------------------
__global__ __launch_bounds__(256) void prep_w(
    const float* __restrict__ w, unsigned short* __restrict__ wP) {
  const int t = blockIdx.x * 256 + threadIdx.x;
  const int j  = t & 7;
  const int l  = (t >> 3) & 63;
  const int m  = (t >> 9) & 3;
  const int ks = t >> 11;                        // 0..17
  const int n  = m * 16 + (l & 15);
  const int k  = ks * 32 + (l >> 4) * 8 + j;
  wP[t] = f32_to_bf16(w[(size_t)n * KC + k]);
}

// ---------------------------------------------------------------------------
// Main kernel. 4 waves/block, 16 pixels; wave wv owns 4 pixels and a private
// LDS slice -> NO barriers anywhere. 18 k-steps of 32.
// Staging: pure global_load_lds DMA, linear LDS dest + pre-permuted per-lane
// global source (lane i of DMA j fetches half (i&1) of xT row ht[px=j][k(i)],
// k(i) = ((i>>3)&3)*8 + (i>>5)*4 + ((i>>1)&3)), reproducing the proven
// tr_b16-readable subtile layout. Double-buffered 16KB halves; counted vmcnt
// (8/4/0); idx prefetched 2 steps ahead.
// Epilogue: direct in-register transpose stores — acc is statically indexed
// EVERYWHERE (the R3-R5 scratch-spill was the runtime-m epilogue alloca
// interacting with the asm "memory" clobbers).
// ---------------------------------------------------------------------------
__global__ __launch_bounds__(256, 3) void hashconv_mfma(
    const int* __restrict__ ht, const unsigned short* __restrict__ xT,
    const unsigned short* __restrict__ wP, float* __restrict__ out) {
  const int tid  = threadIdx.x;
  const int lane = tid & 63;
  const int wv   = __builtin_amdgcn_readfirstlane(tid >> 6);
  const int hi   = lane >> 4;
  const int b16i = lane & 15;
  const int p0   = blockIdx.x * 16;

  __shared__ char Ls[32768];

  // per-lane DMA source decode
  const int kk   = ((lane >> 3) & 3) * 8 + (lane >> 5) * 4 + ((lane >> 1) & 3);
  const int chof = (lane & 1) * 16;   // which 16B half of the 32B xT row

  // tr-read per-lane bases (proven addressing), one per buffer
  const unsigned ldsbase = (unsigned)(size_t)&Ls[0];
  const unsigned trb0 = ldsbase + wv * 4096 + hi * 128 + b16i * 8;
  const unsigned trb1 = trb0 + 16384;

  const int* htj = ht + (size_t)(p0 + 4 * wv) * KC + kk;
  const unsigned short* wPl = wP + lane * 8;
  const char* xTb = (const char*)xT;

  f32x4 acc[4][4];  // [m][px] — statically indexed everywhere
#pragma unroll
  for (int m = 0; m < 4; ++m)
#pragma unroll
    for (int px = 0; px < 4; ++px) acc[m][px] = (f32x4){0.f, 0.f, 0.f, 0.f};

  // ---- prologue: idx(0), idx(1), DMA(0) into buf0 ----
  int i00 = htj[0 * KC], i01 = htj[1 * KC], i02 = htj[2 * KC], i03 = htj[3 * KC];
  int c0 = htj[0 * KC + 32], c1 = htj[1 * KC + 32];
  int c2 = htj[2 * KC + 32], c3 = htj[3 * KC + 32];
  {
    char* db = Ls + (wv << 12);
    gload16(xTb + (size_t)(unsigned)i00 * 32 + chof, db);
    gload16(xTb + (size_t)(unsigned)i01 * 32 + chof, db + 1024);
    gload16(xTb + (size_t)(unsigned)i02 * 32 + chof, db + 2048);
    gload16(xTb + (size_t)(unsigned)i03 * 32 + chof, db + 3072);
  }

#pragma unroll
  for (int st = 0; st < 18; ++st) {
    int n0 = 0, n1 = 0, n2 = 0, n3 = 0;
    // ph1: idx prefetch for st+2
    if (st < 16) {
      n0 = htj[0 * KC + (st + 2) * 32];
      n1 = htj[1 * KC + (st + 2) * 32];
      n2 = htj[2 * KC + (st + 2) * 32];
      n3 = htj[3 * KC + (st + 2) * 32];
    }
    // ph2: DMA gather for st+1 into the other buffer
    if (st < 17) {
      char* db = Ls + (((st + 1) & 1) << 14) + (wv << 12);
      gload16(xTb + (size_t)(unsigned)c0 * 32 + chof, db);
      gload16(xTb + (size_t)(unsigned)c1 * 32 + chof, db + 1024);
      gload16(xTb + (size_t)(unsigned)c2 * 32 + chof, db + 2048);
      gload16(xTb + (size_t)(unsigned)c3 * 32 + chof, db + 3072);
    }
    // ph3: counted drain — this step's DMA done, next step's still in flight
    if (st <= 15)      asm volatile("s_waitcnt vmcnt(8)" ::: "memory");
    else if (st == 16) asm volatile("s_waitcnt vmcnt(4)" ::: "memory");
    else               asm volatile("s_waitcnt vmcnt(0)" ::: "memory");
    // ph4: tr-reads (named scalars only) + MFMA
    const unsigned trb = (st & 1) ? trb1 : trb0;
    i32x2 t00, t01, t10, t11, t20, t21, t30, t31;
    asm volatile("ds_read_b64_tr_b16 %0, %1 offset:0"    : "=v"(t00) : "v"(trb) : "memory");
    asm volatile("ds_read_b64_tr_b16 %0, %1 offset:512"  : "=v"(t01) : "v"(trb) : "memory");
    asm volatile("ds_read_b64_tr_b16 %0, %1 offset:1024" : "=v"(t10) : "v"(trb) : "memory");
    asm volatile("ds_read_b64_tr_b16 %0, %1 offset:1536" : "=v"(t11) : "v"(trb) : "memory");
    asm volatile("ds_read_b64_tr_b16 %0, %1 offset:2048" : "=v"(t20) : "v"(trb) : "memory");
    asm volatile("ds_read_b64_tr_b16 %0, %1 offset:2560" : "=v"(t21) : "v"(trb) : "memory");
    asm volatile("ds_read_b64_tr_b16 %0, %1 offset:3072" : "=v"(t30) : "v"(trb) : "memory");
    asm volatile("ds_read_b64_tr_b16 %0, %1 offset:3584" : "=v"(t31) : "v"(trb) : "memory");
    asm volatile("s_waitcnt lgkmcnt(0)" ::: "memory");
    __builtin_amdgcn_sched_barrier(0);
    const bf16x8 bfr0 = pack_bfr(t00, t01);
    const bf16x8 bfr1 = pack_bfr(t10, t11);
    const bf16x8 bfr2 = pack_bfr(t20, t21);
    const bf16x8 bfr3 = pack_bfr(t30, t31);
#pragma unroll
    for (int m = 0; m < 4; ++m) {
      const bf16x8 afr = *(const bf16x8*)(wPl + (size_t)(st * 4 + m) * 512);
      acc[m][0] = __builtin_amdgcn_mfma_f32_16x16x32_bf16(afr, bfr0, acc[m][0], 0, 0, 0);
      acc[m][1] = __builtin_amdgcn_mfma_f32_16x16x32_bf16(afr, bfr1, acc[m][1], 0, 0, 0);
      acc[m][2] = __builtin_amdgcn_mfma_f32_16x16x32_bf16(afr, bfr2, acc[m][2], 0, 0, 0);
      acc[m][3] = __builtin_amdgcn_mfma_f32_16x16x32_bf16(afr, bfr3, acc[m][3], 0, 0, 0);
    }
    // rotate idx pipeline
    if (st < 16) { c0 = n0; c1 = n1; c2 = n2; c3 = n3; }
  }

  // ---- epilogue: direct in-register transpose stores (all static) ----
  // C/D: col(b16i)=batch b, row in m-tile = hi*4+j, pixel = p0+4wv+px.
  // out[(b*64 + m*16 + hi*4 + j)*NHW + p0 + 4wv + px]; px = float4 lanes.
  // Each 64B output line is filled by the block's 4 waves -> merges in L2.
#pragma unroll
  for (int m = 0; m < 4; ++m)
#pragma unroll
    for (int j = 0; j < 4; ++j) {
      const float4 v = make_float4(acc[m][0][j], acc[m][1][j],
                                   acc[m][2][j], acc[m][3][j]);
      *(float4*)(out +
                 ((size_t)(b16i * 64 + m * 16 + hi * 4 + j)) * NHW +
                 p0 + 4 * wv) = v;
    }
}

// ---------------------------------------------------------------------------
// Fallback (workspace too small): direct gather, slow but correct.
// ---------------------------------------------------------------------------
__global__ __launch_bounds__(256) void hashconv_naive_kernel(
    const int* __restrict__ ht, const float* __restrict__ x,
    const float* __restrict__ w, float* __restrict__ out) {
  const int wave = (blockIdx.x * 256 + threadIdx.x) >> 6;
  const int lane = threadIdx.x & 63;
  const int b = wave >> 14;
  const int p = wave & (NHW - 1);
  float acc = 0.f;
  for (int q = 0; q < KC; ++q) {
    const int idx = __builtin_amdgcn_readlane(ht[(size_t)p * KC + q], 0);
    const float xv = x[(size_t)b * CHW + idx];
    acc = fmaf(w[(size_t)lane * KC + q], xv, acc);
  }
  out[((size_t)(b * 64 + lane)) * NHW + p] = acc;
}

extern "C" void kernel_launch(void* const* d_in, const int* in_sizes, int n_in,
                              void* d_out, int out_size, void* d_ws, size_t ws_size,
                              hipStream_t stream) {
  const float* x  = (const float*)d_in[0];
  const int*   ht = (const int*)d_in[1];
  const float* w  = (const float*)d_in[2];
  float* out = (float*)d_out;

  const size_t xT_elems = (size_t)CHW * NB;      // bf16
  const size_t wP_elems = (size_t)18 * 4 * 64 * 8;
  const size_t need = (xT_elems + wP_elems) * sizeof(unsigned short);

  if (ws_size >= need) {
    unsigned short* xT = (unsigned short*)d_ws;
    unsigned short* wP = xT + xT_elems;
    transpose_x_bf16<<<CHW / 256, 256, 0, stream>>>(x, xT);
    prep_w<<<(int)(wP_elems / 256), 256, 0, stream>>>(w, wP);
    hashconv_mfma<<<NHW / 16, 256, 0, stream>>>(ht, xT, wP, out);
  } else {
    hashconv_naive_kernel<<<(NB * NHW * 64) / 256, 256, 0, stream>>>(ht, x, w, out);
  }
}